// Round 4
// baseline (886.347 us; speedup 1.0000x reference)
//
#include <hip/hip_runtime.h>
#include <stdint.h>

#define NN 8192
#define DD 128
#define GRID 512

typedef float f32x4 __attribute__((ext_vector_type(4)));
typedef short bf16x8 __attribute__((ext_vector_type(8)));

union B8 { uint32_t u[4]; bf16x8 v; };

__device__ inline uint16_t f2bf(float f) {
  uint32_t u = __builtin_bit_cast(uint32_t, f);
  uint32_t r = (u + 0x7FFFu + ((u >> 16) & 1u)) >> 16;
  return (uint16_t)r;
}

__device__ inline f32x4 mfma16(bf16x8 a, bf16x8 b, f32x4 c) {
  return __builtin_amdgcn_mfma_f32_16x16x32_bf16(a, b, c, 0, 0, 0);
}

// async global->LDS, 16B per lane, dest = wave-uniform base + lane*16
__device__ inline void gl_lds16(const uint16_t* g, uint16_t* l) {
  __builtin_amdgcn_global_load_lds((const __attribute__((address_space(1))) void*)g,
                                   (__attribute__((address_space(3))) void*)l, 16, 0, 0);
}

// Grid barrier: monotonic count, no reset (counter zeroed per-launch via hipMemsetAsync).
// Release fence before signal, acquire fence after; device-scope atomics (cross-XCD safe).
__device__ inline void gbar(uint32_t* cnt, uint32_t tgt) {
  __syncthreads();
  __threadfence();  // release: flush this block's writes device-wide
  if (threadIdx.x == 0) {
    atomicAdd(cnt, 1u);
    while (atomicAdd(cnt, 0u) < tgt) __builtin_amdgcn_s_sleep(8);
  }
  __syncthreads();
  __threadfence();  // acquire: invalidate stale cached lines
}

__global__ __launch_bounds__(256, 2) void k_mega(const float* __restrict__ inp,
                                                 const int* __restrict__ sim,
                                                 uint16_t* __restrict__ inp_bf,
                                                 uint16_t* __restrict__ inpT_bf,
                                                 float* __restrict__ x2p,
                                                 uint32_t* __restrict__ bmT,
                                                 uint32_t* __restrict__ counts,
                                                 float* __restrict__ part,
                                                 float* __restrict__ centers,
                                                 uint16_t* __restrict__ cen_bf,
                                                 uint32_t* __restrict__ negkey,
                                                 float* __restrict__ out,
                                                 uint32_t* __restrict__ bar) {
  __shared__ __align__(16) uint8_t smem[32768];
  const int tid = threadIdx.x;
  const int bid = blockIdx.x;
  const int lane = tid & 63, w = tid >> 6;
  const int col = lane & 15, quad = lane >> 4;

  // ================= Phase A: prep (blocks 0..127) + bitgen (all 512) =================
  if (bid < 128) {
    uint16_t* ldsT = (uint16_t*)smem;        // 128*65 shorts = 16640 B
    float* ldsS = (float*)(smem + 16640);    // 256 floats
    const int gid = bid * 256 + tid;
    if (gid < NN) negkey[gid] = 0xFFFFFFFFu;
    if (gid == 0) out[0] = 0.f;
    const int j0 = bid * 64;
    const int r = tid >> 2;
    const int dseg = (tid & 3) * 32;
    float ss = 0.f;
#pragma unroll
    for (int it = 0; it < 8; ++it) {
      float4 v = *(const float4*)(inp + (size_t)(j0 + r) * DD + dseg + it * 4);
      ss += v.x * v.x + v.y * v.y + v.z * v.z + v.w * v.w;
      uint16_t b0 = f2bf(v.x), b1 = f2bf(v.y), b2 = f2bf(v.z), b3 = f2bf(v.w);
      *(ushort4*)(inp_bf + (size_t)(j0 + r) * DD + dseg + it * 4) = make_ushort4(b0, b1, b2, b3);
      int d = dseg + it * 4;
      ldsT[(d + 0) * 65 + r] = b0;
      ldsT[(d + 1) * 65 + r] = b1;
      ldsT[(d + 2) * 65 + r] = b2;
      ldsT[(d + 3) * 65 + r] = b3;
    }
    ldsS[tid] = ss;
    __syncthreads();
    if (tid < 64)
      x2p[j0 + tid] = ldsS[tid * 4] + ldsS[tid * 4 + 1] + ldsS[tid * 4 + 2] + ldsS[tid * 4 + 3] + 512.0f;
#pragma unroll
    for (int it = 0; it < 32; ++it) {
      int flat = it * 256 + tid;
      int d = flat >> 6, jl = flat & 63;
      inpT_bf[(size_t)d * NN + j0 + jl] = ldsT[d * 65 + jl];
    }
    __syncthreads();  // smem handoff to bitgen
  }
  {
    uint32_t* ldsW = (uint32_t*)smem;  // 64*64 words = 16 KB
    const int m0 = (bid & 127) * 64;
    const int c0 = (bid >> 7) * 2048;
    int va[32], vb[32];
    {
      const int* p = sim + (size_t)(m0 + w) * NN + c0 + lane;
#pragma unroll
      for (int s = 0; s < 32; ++s) va[s] = p[s * 64];
    }
#pragma unroll 1
    for (int rr = 0; rr < 16; ++rr) {
      const int rl = rr * 4 + w;
      if (rr < 15) {
        const int* p = sim + (size_t)(m0 + rl + 4) * NN + c0 + lane;
#pragma unroll
        for (int s = 0; s < 32; ++s) vb[s] = p[s * 64];
      }
      uint32_t cnt = 0;
#pragma unroll
      for (int s = 0; s < 32; ++s) {
        unsigned long long ball = __ballot(va[s] != 0);
        cnt += (uint32_t)__popcll(ball);
        if ((lane & 31) == 0)
          ldsW[(s * 2 + (lane >> 5)) * 64 + rl] = (uint32_t)(ball >> (lane & 32));
      }
      if (lane == 0) atomicAdd(&counts[m0 + rl], cnt);
#pragma unroll
      for (int s = 0; s < 32; ++s) va[s] = vb[s];
    }
    __syncthreads();
#pragma unroll
    for (int it = 0; it < 16; ++it) {
      int idx = it * 256 + tid;
      int kw = idx >> 6, r = idx & 63;
      bmT[(size_t)((c0 >> 5) + kw) * NN + m0 + r] = ldsW[idx];
    }
  }
  gbar(bar, 1 * GRID);

  // ================= Phase B: gemm1 (centers partials, m97-style) =================
  {
    uint16_t (*ldsB)[128 * 64] = (uint16_t(*)[128 * 64])smem;  // 2 x 16 KB
    const int bx = bid & 63, by = bid >> 6;
    const int m0 = bx * 128;
    const int kb0 = by * 1024;
    const int wm = (w >> 1) * 64, wn = (w & 1) * 64;
    const int swz = (col & 7) << 4;
    f32x4 acc[4][4];
    const f32x4 z = {0.f, 0.f, 0.f, 0.f};
#pragma unroll
    for (int r = 0; r < 4; ++r)
#pragma unroll
      for (int c = 0; c < 4; ++c) acc[r][c] = z;

    uint32_t mwA[8], mwB[8];
    const int srow = lane >> 3;
    const int schk = (lane & 7) ^ (srow & 7);

#define STAGE3(BUF, KB)                                                                       \
  {                                                                                           \
    _Pragma("unroll") for (int c = 0; c < 4; ++c) {                                           \
      const uint16_t* gsrc =                                                                  \
          inpT_bf + (size_t)(w * 32 + c * 8 + srow) * NN + (KB) + (schk << 3);                \
      gl_lds16(gsrc, &ldsB[BUF][(w * 32 + c * 8) * 64]);                                      \
    }                                                                                         \
  }

#define LDM3(MW, KB)                                                                          \
  {                                                                                           \
    _Pragma("unroll") for (int rr = 0; rr < 4; ++rr)                                          \
      _Pragma("unroll") for (int h = 0; h < 2; ++h)                                           \
        MW[rr * 2 + h] = bmT[(size_t)(((KB) >> 5) + h) * NN + m0 + wm + rr * 16 + col];       \
  }

#define COMP3(BUF, MW)                                                                        \
  {                                                                                           \
    _Pragma("unroll") for (int h = 0; h < 2; ++h) {                                           \
      B8 af[4];                                                                               \
      _Pragma("unroll") for (int rr = 0; rr < 4; ++rr) {                                      \
        uint32_t word = MW[rr * 2 + h];                                                       \
        uint32_t b = (word >> (quad * 8)) & 0xFFu;                                            \
        uint32_t s = b * 0x8001u;                                                             \
        _Pragma("unroll") for (int p = 0; p < 4; ++p)                                         \
          af[rr].u[p] = ((s >> (2 * p)) & 0x10001u) * 0x3F80u;                                \
      }                                                                                       \
      const int eoff = ((h * 64 + quad * 16) ^ swz) >> 1;                                     \
      _Pragma("unroll") for (int cc = 0; cc < 4; ++cc) {                                      \
        bf16x8 bfr = *(const bf16x8*)(&ldsB[BUF][(wn + cc * 16 + col) * 64 + eoff]);          \
        _Pragma("unroll") for (int rr = 0; rr < 4; ++rr)                                      \
          acc[rr][cc] = mfma16(af[rr].v, bfr, acc[rr][cc]);                                   \
      }                                                                                       \
    }                                                                                         \
  }

    STAGE3(0, kb0);
    LDM3(mwA, kb0);
    __syncthreads();
#pragma unroll 1
    for (int ks = 0; ks < 16; ks += 2) {
      const int kb = kb0 + ks * 64;
      STAGE3(1, kb + 64);
      LDM3(mwB, kb + 64);
      COMP3(0, mwA);
      __syncthreads();
      if (ks + 2 < 16) {
        STAGE3(0, kb + 128);
        LDM3(mwA, kb + 128);
      }
      COMP3(1, mwB);
      __syncthreads();
    }
#undef STAGE3
#undef LDM3
#undef COMP3

    float* pp = part + (size_t)by * NN * DD;
#pragma unroll
    for (int rr = 0; rr < 4; ++rr)
#pragma unroll
      for (int cc = 0; cc < 4; ++cc)
#pragma unroll
        for (int g = 0; g < 4; ++g)
          pp[(size_t)(m0 + wm + rr * 16 + quad * 4 + g) * DD + wn + cc * 16 + col] = acc[rr][cc][g];
  }
  gbar(bar, 2 * GRID);

  // ================= Phase C: reduce partials -> centers (2 float4 / thread) =================
  {
#pragma unroll 1
    for (int rep = 0; rep < 2; ++rep) {
      const int fg = rep * 131072 + bid * 256 + tid;
      const int idx = fg * 4;
      const int row = idx >> 7;
      const float inv = 1.0f / (float)counts[row];
      float4 v = *(const float4*)(part + idx);
#pragma unroll
      for (int s = 1; s < 8; ++s) {
        float4 u = *(const float4*)(part + (size_t)s * NN * DD + idx);
        v.x += u.x; v.y += u.y; v.z += u.z; v.w += u.w;
      }
      v.x *= inv; v.y *= inv; v.z *= inv; v.w *= inv;
      *(float4*)(centers + idx) = v;
      *(ushort4*)(cen_bf + idx) = make_ushort4(f2bf(v.x), f2bf(v.y), f2bf(v.z), f2bf(v.w));
    }
  }
  gbar(bar, 3 * GRID);

  // ================= Phase D: dist-GEMM + masked argmin =================
  {
    uint16_t (*ldsX)[64 * 128] = (uint16_t(*)[64 * 128])smem;  // 2 x 16 KB
    const int bx = bid & 63, by = bid >> 6;
    const int i0 = bx * 128;
    const int jbase = by * 1024;
    const int wi = w * 32;
    const int swz = (col & 7) << 4;

    bf16x8 af[2][4];
#pragma unroll
    for (int rr = 0; rr < 2; ++rr)
#pragma unroll
      for (int kk = 0; kk < 4; ++kk)
        af[rr][kk] = *(const bf16x8*)(cen_bf + (size_t)(i0 + wi + rr * 16 + col) * DD + kk * 32 + quad * 8);

    uint32_t best[2][4];
#pragma unroll
    for (int rr = 0; rr < 2; ++rr)
#pragma unroll
      for (int g = 0; g < 4; ++g) best[rr][g] = 0xFFFFFFFFu;

    const f32x4 z = {0.f, 0.f, 0.f, 0.f};
    const int srow = lane >> 4;  // 0..3

#define STAGE5(BUF, J0)                                                                       \
  {                                                                                           \
    _Pragma("unroll") for (int c = 0; c < 4; ++c) {                                           \
      const int r7 = (c * 4 + srow) & 7;                                                      \
      const uint16_t* gsrc =                                                                  \
          inp_bf + (size_t)((J0) + w * 16 + c * 4 + srow) * DD + (((lane & 15) ^ r7) << 3);   \
      gl_lds16(gsrc, &ldsX[BUF][(w * 16 + c * 4) * 128]);                                     \
    }                                                                                         \
  }

#define COMP5(BUF, J0)                                                                        \
  {                                                                                           \
    uint32_t mw[2][2][4];                                                                     \
    float xv[4];                                                                              \
    _Pragma("unroll") for (int h = 0; h < 2; ++h)                                             \
      _Pragma("unroll") for (int rr = 0; rr < 2; ++rr)                                        \
        _Pragma("unroll") for (int g = 0; g < 4; ++g)                                         \
          mw[h][rr][g] =                                                                      \
              bmT[(size_t)(((J0) >> 5) + h) * NN + i0 + wi + rr * 16 + quad * 4 + g];         \
    _Pragma("unroll") for (int cc = 0; cc < 4; ++cc) xv[cc] = x2p[(J0) + cc * 16 + col];      \
    f32x4 acc[2][4];                                                                          \
    _Pragma("unroll") for (int rr = 0; rr < 2; ++rr)                                          \
      _Pragma("unroll") for (int cc = 0; cc < 4; ++cc) acc[rr][cc] = z;                       \
    _Pragma("unroll") for (int kk = 0; kk < 4; ++kk) {                                        \
      const int eoff = ((kk * 64 + quad * 16) ^ swz) >> 1;                                    \
      _Pragma("unroll") for (int cc = 0; cc < 4; ++cc) {                                      \
        bf16x8 b = *(const bf16x8*)(&ldsX[BUF][(cc * 16 + col) * 128 + eoff]);                \
        acc[0][cc] = mfma16(af[0][kk], b, acc[0][cc]);                                        \
        acc[1][cc] = mfma16(af[1][kk], b, acc[1][cc]);                                        \
      }                                                                                       \
    }                                                                                         \
    _Pragma("unroll") for (int cc = 0; cc < 4; ++cc) {                                        \
      const int jj = cc * 16 + col;                                                           \
      const float xq = xv[cc];                                                                \
      const uint32_t jpre = (uint32_t)((J0) + jj);                                            \
      const int sh = 31 - ((cc & 1) * 16 + col);                                              \
      _Pragma("unroll") for (int rr = 0; rr < 2; ++rr)                                        \
        _Pragma("unroll") for (int g = 0; g < 4; ++g) {                                       \
          float v = fmaf(-2.0f, acc[rr][cc][g], xq);                                          \
          uint32_t u = __builtin_bit_cast(uint32_t, v);                                       \
          uint32_t key = (u & 0xFFFFE000u) | jpre;                                            \
          key |= (mw[cc >> 1][rr][g] << sh) & 0x80000000u;                                    \
          best[rr][g] = min(best[rr][g], key);                                                \
        }                                                                                     \
    }                                                                                         \
  }

    STAGE5(0, jbase);
    __syncthreads();
#pragma unroll 1
    for (int st = 0; st < 16; st += 2) {
      const int j0 = jbase + st * 64;
      STAGE5(1, j0 + 64);
      COMP5(0, j0);
      __syncthreads();
      if (st + 2 < 16) STAGE5(0, j0 + 128);
      COMP5(1, j0 + 64);
      __syncthreads();
    }
#undef STAGE5
#undef COMP5

#pragma unroll
    for (int rr = 0; rr < 2; ++rr)
#pragma unroll
      for (int g = 0; g < 4; ++g) {
        uint32_t k = best[rr][g];
#pragma unroll
        for (int d = 1; d < 16; d <<= 1) {
          uint32_t o = (uint32_t)__shfl_xor((int)k, d);
          k = min(k, o);
        }
        if (col == 0) atomicMin(&negkey[i0 + wi + rr * 16 + quad * 4 + g], k);
      }
  }
  gbar(bar, 4 * GRID);

  // ================= Phase E: triplet loss (exact fp32), wave-per-anchor =================
  {
    float* ldsL = (float*)smem;
    float local = 0.f;
#pragma unroll 1
    for (int a = 0; a < 4; ++a) {
      int i = bid * 16 + w * 4 + a;
      float2 c = *(const float2*)(centers + (size_t)i * DD + lane * 2);
      float2 x = *(const float2*)(inp + (size_t)i * DD + lane * 2);
      uint32_t ni = negkey[i] & (NN - 1);
      float2 gv = *(const float2*)(inp + (size_t)ni * DD + lane * 2);
      float e0 = c.x - x.x + 1e-6f, e1 = c.y - x.y + 1e-6f;
      float f0 = c.x - gv.x + 1e-6f, f1 = c.y - gv.y + 1e-6f;
      float dap = e0 * e0 + e1 * e1;
      float dan = f0 * f0 + f1 * f1;
#pragma unroll
      for (int d = 32; d; d >>= 1) {
        dap += __shfl_down(dap, d);
        dan += __shfl_down(dan, d);
      }
      if (lane == 0) local += fmaxf(sqrtf(dap) - sqrtf(dan) + 0.3f, 0.f);
    }
    if (lane == 0) ldsL[w] = local;
    __syncthreads();
    if (tid == 0) atomicAdd(out, (ldsL[0] + ldsL[1] + ldsL[2] + ldsL[3]) * (1.0f / 8192.0f));
  }
}

extern "C" void kernel_launch(void* const* d_in, const int* in_sizes, int n_in,
                              void* d_out, int out_size, void* d_ws, size_t ws_size,
                              hipStream_t stream) {
  (void)in_sizes; (void)n_in; (void)out_size; (void)ws_size;
  const float* inp = (const float*)d_in[0];
  const int* sim = (const int*)d_in[1];
  float* out = (float*)d_out;
  char* ws = (char*)d_ws;

  uint32_t* bmT     = (uint32_t*)ws;                                   // 8 MB  [kword][row]
  float* part       = (float*)(ws + (8u << 20));                       // 32 MB (8 K-splits)
  float* centers    = (float*)(ws + (40u << 20));                      // 4 MB
  uint16_t* inp_bf  = (uint16_t*)(ws + (44u << 20));                   // 2 MB
  uint16_t* inpT_bf = (uint16_t*)(ws + (46u << 20));                   // 2 MB
  uint16_t* cen_bf  = (uint16_t*)(ws + (48u << 20));                   // 2 MB
  float* x2p        = (float*)(ws + (50u << 20));                      // 32 KB
  uint32_t* counts  = (uint32_t*)(ws + (50u << 20) + 32768u);          // 32 KB
  uint32_t* negkey  = (uint32_t*)(ws + (50u << 20) + 65536u);          // 32 KB
  uint32_t* bar     = (uint32_t*)(ws + (50u << 20) + 98304u);          // 64 B

  hipMemsetAsync(counts, 0, 32768, stream);
  hipMemsetAsync(bar, 0, 64, stream);
  k_mega<<<GRID, 256, 0, stream>>>(inp, sim, inp_bf, inpT_bf, x2p, bmT, counts, part,
                                   centers, cen_bf, negkey, out, bar);
}

// Round 5
// 440.725 us; speedup vs baseline: 2.0111x; 2.0111x over previous
//
#include <hip/hip_runtime.h>
#include <stdint.h>

#define NN 8192
#define DD 128

typedef float f32x4 __attribute__((ext_vector_type(4)));
typedef short bf16x8 __attribute__((ext_vector_type(8)));

union B8 { uint32_t u[4]; bf16x8 v; };

__device__ inline uint16_t f2bf(float f) {
  uint32_t u = __builtin_bit_cast(uint32_t, f);
  uint32_t r = (u + 0x7FFFu + ((u >> 16) & 1u)) >> 16;
  return (uint16_t)r;
}

__device__ inline f32x4 mfma16(bf16x8 a, bf16x8 b, f32x4 c) {
  return __builtin_amdgcn_mfma_f32_16x16x32_bf16(a, b, c, 0, 0, 0);
}

// async global->LDS, 16B per lane, dest = wave-uniform base + lane*16
__device__ inline void gl_lds16(const uint16_t* g, uint16_t* l) {
  __builtin_amdgcn_global_load_lds((const __attribute__((address_space(1))) void*)g,
                                   (__attribute__((address_space(3))) void*)l, 16, 0, 0);
}

// ---- K12 fused: blocks [0,128) = prep (bf16 copies + x2 + inits),
//      blocks [128,640) = bitgen (sim -> column-major bitmask + per-slice counts).
//      Independent work; counts4[slice][row] is a plain store (1 writer/slot),
//      so no zeroing and no atomics are needed (removes the K1/K2 race).
__global__ __launch_bounds__(256, 2) void k_prep_bitgen(const float* __restrict__ inp,
                                                        const int* __restrict__ sim,
                                                        uint16_t* __restrict__ inp_bf,
                                                        uint16_t* __restrict__ inpT_bf,
                                                        float* __restrict__ x2p,
                                                        uint32_t* __restrict__ bmT,
                                                        uint32_t* __restrict__ counts4,
                                                        uint32_t* __restrict__ negkey,
                                                        float* __restrict__ out) {
  __shared__ uint32_t shmem[4416];  // 17.7 KB, overlaid per branch
  const int tid = threadIdx.x;
  const int bid = blockIdx.x;
  if (bid < 128) {
    // ---------------- prep branch ----------------
    uint16_t* ldsT = (uint16_t*)shmem;          // 128*65 shorts = 16640 B
    float* ldsS = (float*)(shmem + 4160);       // 256 floats
    const int gid = bid * 256 + tid;
    if (gid < NN) negkey[gid] = 0xFFFFFFFFu;
    if (gid == 0) out[0] = 0.f;
    const int j0 = bid * 64;
    const int r = tid >> 2;
    const int dseg = (tid & 3) * 32;
    float ss = 0.f;
#pragma unroll
    for (int it = 0; it < 8; ++it) {
      float4 v = *(const float4*)(inp + (size_t)(j0 + r) * DD + dseg + it * 4);
      ss += v.x * v.x + v.y * v.y + v.z * v.z + v.w * v.w;
      uint16_t b0 = f2bf(v.x), b1 = f2bf(v.y), b2 = f2bf(v.z), b3 = f2bf(v.w);
      *(ushort4*)(inp_bf + (size_t)(j0 + r) * DD + dseg + it * 4) = make_ushort4(b0, b1, b2, b3);
      int d = dseg + it * 4;
      ldsT[(d + 0) * 65 + r] = b0;
      ldsT[(d + 1) * 65 + r] = b1;
      ldsT[(d + 2) * 65 + r] = b2;
      ldsT[(d + 3) * 65 + r] = b3;
    }
    ldsS[tid] = ss;
    __syncthreads();
    if (tid < 64)
      x2p[j0 + tid] = ldsS[tid * 4] + ldsS[tid * 4 + 1] + ldsS[tid * 4 + 2] + ldsS[tid * 4 + 3] + 512.0f;
#pragma unroll
    for (int it = 0; it < 32; ++it) {
      int flat = it * 256 + tid;
      int d = flat >> 6, jl = flat & 63;
      inpT_bf[(size_t)d * NN + j0 + jl] = ldsT[d * 65 + jl];
    }
  } else {
    // ---------------- bitgen branch (R2-K2 core, counts -> plain partial store) ----------------
    uint32_t* ldsW = shmem;  // 64*64 words = 16 KB
    const int bx = bid - 128;
    const int lane = tid & 63, w = tid >> 6;
    const int m0 = (bx & 127) * 64;
    const int c0 = (bx >> 7) * 2048;
    const int slice = bx >> 7;
    int va[32], vb[32];
    {
      const int* p = sim + (size_t)(m0 + w) * NN + c0 + lane;
#pragma unroll
      for (int s = 0; s < 32; ++s) va[s] = p[s * 64];
    }
#pragma unroll 1
    for (int rr = 0; rr < 16; ++rr) {
      const int rl = rr * 4 + w;
      if (rr < 15) {
        const int* p = sim + (size_t)(m0 + rl + 4) * NN + c0 + lane;
#pragma unroll
        for (int s = 0; s < 32; ++s) vb[s] = p[s * 64];
      }
      uint32_t cnt = 0;
#pragma unroll
      for (int s = 0; s < 32; ++s) {
        unsigned long long ball = __ballot(va[s] != 0);
        cnt += (uint32_t)__popcll(ball);
        if ((lane & 31) == 0)
          ldsW[(s * 2 + (lane >> 5)) * 64 + rl] = (uint32_t)(ball >> (lane & 32));
      }
      if (lane == 0) counts4[(size_t)slice * NN + m0 + rl] = cnt;
#pragma unroll
      for (int s = 0; s < 32; ++s) va[s] = vb[s];
    }
    __syncthreads();
#pragma unroll
    for (int it = 0; it < 16; ++it) {
      int idx = it * 256 + tid;
      int kw = idx >> 6, r = idx & 63;
      bmT[(size_t)((c0 >> 5) + kw) * NN + m0 + r] = ldsW[idx];
    }
  }
}

// ---- K3 (R2 verbatim, m97-style): centers partials = mask @ inputs.
__global__ __launch_bounds__(256, 2) void k_gemm1(const uint16_t* __restrict__ inpT,
                                                  const uint32_t* __restrict__ bmT,
                                                  float* __restrict__ part) {
  __shared__ __align__(16) uint16_t ldsB[2][128 * 64];  // 2 x 16 KB, linear (gload_lds)
  const int tid = threadIdx.x, lane = tid & 63, w = tid >> 6;
  const int col = lane & 15, quad = lane >> 4;
  const int m0 = blockIdx.x * 128;
  const int kb0 = blockIdx.y * 1024;
  const int wm = (w >> 1) * 64, wn = (w & 1) * 64;
  const int swz = (col & 7) << 4;  // read-side byte XOR
  f32x4 acc[4][4];
  const f32x4 z = {0.f, 0.f, 0.f, 0.f};
#pragma unroll
  for (int r = 0; r < 4; ++r)
#pragma unroll
    for (int c = 0; c < 4; ++c) acc[r][c] = z;

  uint32_t mwA[8], mwB[8];
  const int srow = lane >> 3;
  const int schk = (lane & 7) ^ (srow & 7);

#define STAGE3(BUF, KB)                                                                       \
  {                                                                                           \
    _Pragma("unroll") for (int c = 0; c < 4; ++c) {                                           \
      const uint16_t* gsrc =                                                                  \
          inpT + (size_t)(w * 32 + c * 8 + srow) * NN + (KB) + (schk << 3);                   \
      gl_lds16(gsrc, &ldsB[BUF][(w * 32 + c * 8) * 64]);                                      \
    }                                                                                         \
  }

#define LDM3(MW, KB)                                                                          \
  {                                                                                           \
    _Pragma("unroll") for (int rr = 0; rr < 4; ++rr)                                          \
      _Pragma("unroll") for (int h = 0; h < 2; ++h)                                           \
        MW[rr * 2 + h] = bmT[(size_t)(((KB) >> 5) + h) * NN + m0 + wm + rr * 16 + col];       \
  }

#define COMP3(BUF, MW)                                                                        \
  {                                                                                           \
    _Pragma("unroll") for (int h = 0; h < 2; ++h) {                                           \
      B8 af[4];                                                                               \
      _Pragma("unroll") for (int rr = 0; rr < 4; ++rr) {                                      \
        uint32_t word = MW[rr * 2 + h];                                                       \
        uint32_t b = (word >> (quad * 8)) & 0xFFu;                                            \
        uint32_t s = b * 0x8001u;                                                             \
        _Pragma("unroll") for (int p = 0; p < 4; ++p)                                         \
          af[rr].u[p] = ((s >> (2 * p)) & 0x10001u) * 0x3F80u;                                \
      }                                                                                       \
      const int eoff = ((h * 64 + quad * 16) ^ swz) >> 1;                                     \
      _Pragma("unroll") for (int cc = 0; cc < 4; ++cc) {                                      \
        bf16x8 bfr = *(const bf16x8*)(&ldsB[BUF][(wn + cc * 16 + col) * 64 + eoff]);          \
        _Pragma("unroll") for (int rr = 0; rr < 4; ++rr)                                      \
          acc[rr][cc] = mfma16(af[rr].v, bfr, acc[rr][cc]);                                   \
      }                                                                                       \
    }                                                                                         \
  }

  STAGE3(0, kb0);
  LDM3(mwA, kb0);
  __syncthreads();
#pragma unroll 1
  for (int ks = 0; ks < 16; ks += 2) {
    const int kb = kb0 + ks * 64;
    STAGE3(1, kb + 64);
    LDM3(mwB, kb + 64);
    COMP3(0, mwA);
    __syncthreads();
    if (ks + 2 < 16) {
      STAGE3(0, kb + 128);
      LDM3(mwA, kb + 128);
    }
    COMP3(1, mwB);
    __syncthreads();
  }
#undef STAGE3
#undef LDM3
#undef COMP3

  float* pp = part + (size_t)blockIdx.y * NN * DD;
#pragma unroll
  for (int rr = 0; rr < 4; ++rr)
#pragma unroll
    for (int cc = 0; cc < 4; ++cc)
#pragma unroll
      for (int g = 0; g < 4; ++g)
        pp[(size_t)(m0 + wm + rr * 16 + quad * 4 + g) * DD + wn + cc * 16 + col] = acc[rr][cc][g];
}

// ---- K4: reduce 8 partials, divide by summed counts4, emit fp32 + bf16 centers ----
__global__ __launch_bounds__(256) void k_reduce(const float* __restrict__ part,
                                                const uint32_t* __restrict__ counts4,
                                                float* __restrict__ centers,
                                                uint16_t* __restrict__ cen_bf) {
  const int gid = blockIdx.x * 256 + threadIdx.x;
  const int idx = gid * 4;
  const int row = idx >> 7;
  const uint32_t cnt = counts4[row] + counts4[NN + row] + counts4[2 * NN + row] + counts4[3 * NN + row];
  const float inv = 1.0f / (float)cnt;
  float4 v = *(const float4*)(part + idx);
#pragma unroll
  for (int s = 1; s < 8; ++s) {
    float4 u = *(const float4*)(part + (size_t)s * NN * DD + idx);
    v.x += u.x; v.y += u.y; v.z += u.z; v.w += u.w;
  }
  v.x *= inv; v.y *= inv; v.z *= inv; v.w *= inv;
  *(float4*)(centers + idx) = v;
  *(ushort4*)(cen_bf + idx) = make_ushort4(f2bf(v.x), f2bf(v.y), f2bf(v.z), f2bf(v.w));
}

// ---- K5 (R2 verbatim, m97-style): fused dist-GEMM + masked hard-negative argmin ----
__global__ __launch_bounds__(256, 2) void k_argmin(const uint16_t* __restrict__ cen_bf,
                                                   const uint16_t* __restrict__ inp_bf,
                                                   const uint32_t* __restrict__ bmT,
                                                   const float* __restrict__ x2p,
                                                   uint32_t* __restrict__ negkey) {
  __shared__ __align__(16) uint16_t ldsX[2][64 * 128];  // 2 x 16 KB, linear
  const int tid = threadIdx.x, lane = tid & 63, w = tid >> 6;
  const int col = lane & 15, quad = lane >> 4;
  const int i0 = blockIdx.x * 128;
  const int jbase = blockIdx.y * 1024;
  const int wi = w * 32;
  const int swz = (col & 7) << 4;

  bf16x8 af[2][4];
#pragma unroll
  for (int rr = 0; rr < 2; ++rr)
#pragma unroll
    for (int kk = 0; kk < 4; ++kk)
      af[rr][kk] = *(const bf16x8*)(cen_bf + (size_t)(i0 + wi + rr * 16 + col) * DD + kk * 32 + quad * 8);

  uint32_t best[2][4];
#pragma unroll
  for (int rr = 0; rr < 2; ++rr)
#pragma unroll
    for (int g = 0; g < 4; ++g) best[rr][g] = 0xFFFFFFFFu;

  const f32x4 z = {0.f, 0.f, 0.f, 0.f};
  const int srow = lane >> 4;  // 0..3

#define STAGE5(BUF, J0)                                                                       \
  {                                                                                           \
    _Pragma("unroll") for (int c = 0; c < 4; ++c) {                                           \
      const int r7 = (c * 4 + srow) & 7;                                                      \
      const uint16_t* gsrc =                                                                  \
          inp_bf + (size_t)((J0) + w * 16 + c * 4 + srow) * DD + (((lane & 15) ^ r7) << 3);   \
      gl_lds16(gsrc, &ldsX[BUF][(w * 16 + c * 4) * 128]);                                     \
    }                                                                                         \
  }

#define COMP5(BUF, J0)                                                                        \
  {                                                                                           \
    uint32_t mw[2][2][4];                                                                     \
    float xv[4];                                                                              \
    _Pragma("unroll") for (int h = 0; h < 2; ++h)                                             \
      _Pragma("unroll") for (int rr = 0; rr < 2; ++rr)                                        \
        _Pragma("unroll") for (int g = 0; g < 4; ++g)                                         \
          mw[h][rr][g] =                                                                      \
              bmT[(size_t)(((J0) >> 5) + h) * NN + i0 + wi + rr * 16 + quad * 4 + g];         \
    _Pragma("unroll") for (int cc = 0; cc < 4; ++cc) xv[cc] = x2p[(J0) + cc * 16 + col];      \
    f32x4 acc[2][4];                                                                          \
    _Pragma("unroll") for (int rr = 0; rr < 2; ++rr)                                          \
      _Pragma("unroll") for (int cc = 0; cc < 4; ++cc) acc[rr][cc] = z;                       \
    _Pragma("unroll") for (int kk = 0; kk < 4; ++kk) {                                        \
      const int eoff = ((kk * 64 + quad * 16) ^ swz) >> 1;                                    \
      _Pragma("unroll") for (int cc = 0; cc < 4; ++cc) {                                      \
        bf16x8 b = *(const bf16x8*)(&ldsX[BUF][(cc * 16 + col) * 128 + eoff]);                \
        acc[0][cc] = mfma16(af[0][kk], b, acc[0][cc]);                                        \
        acc[1][cc] = mfma16(af[1][kk], b, acc[1][cc]);                                        \
      }                                                                                       \
    }                                                                                         \
    _Pragma("unroll") for (int cc = 0; cc < 4; ++cc) {                                        \
      const int jj = cc * 16 + col;                                                           \
      const float xq = xv[cc];                                                                \
      const uint32_t jpre = (uint32_t)((J0) + jj);                                            \
      const int sh = 31 - ((cc & 1) * 16 + col);                                              \
      _Pragma("unroll") for (int rr = 0; rr < 2; ++rr)                                        \
        _Pragma("unroll") for (int g = 0; g < 4; ++g) {                                       \
          float v = fmaf(-2.0f, acc[rr][cc][g], xq);                                          \
          uint32_t u = __builtin_bit_cast(uint32_t, v);                                       \
          uint32_t key = (u & 0xFFFFE000u) | jpre;                                            \
          key |= (mw[cc >> 1][rr][g] << sh) & 0x80000000u;                                    \
          best[rr][g] = min(best[rr][g], key);                                                \
        }                                                                                     \
    }                                                                                         \
  }

  STAGE5(0, jbase);
  __syncthreads();
#pragma unroll 1
  for (int st = 0; st < 16; st += 2) {
    const int j0 = jbase + st * 64;
    STAGE5(1, j0 + 64);
    COMP5(0, j0);
    __syncthreads();
    if (st + 2 < 16) STAGE5(0, j0 + 128);
    COMP5(1, j0 + 64);
    __syncthreads();
  }
#undef STAGE5
#undef COMP5

#pragma unroll
  for (int rr = 0; rr < 2; ++rr)
#pragma unroll
    for (int g = 0; g < 4; ++g) {
      uint32_t k = best[rr][g];
#pragma unroll
      for (int d = 1; d < 16; d <<= 1) {
        uint32_t o = (uint32_t)__shfl_xor((int)k, d);
        k = min(k, o);
      }
      if (col == 0) atomicMin(&negkey[i0 + wi + rr * 16 + quad * 4 + g], k);
    }
}

// ---------------- K6: triplet loss (exact fp32), wave-per-anchor ----------------
__global__ __launch_bounds__(256) void k_loss(const float* __restrict__ centers,
                                              const float* __restrict__ inp,
                                              const uint32_t* __restrict__ negkey,
                                              float* __restrict__ out) {
  __shared__ float lds[4];
  const int tid = threadIdx.x, lane = tid & 63, w = tid >> 6;
  float local = 0.f;
#pragma unroll 1
  for (int a = 0; a < 4; ++a) {
    int i = blockIdx.x * 16 + w * 4 + a;
    float2 c = *(const float2*)(centers + (size_t)i * DD + lane * 2);
    float2 x = *(const float2*)(inp + (size_t)i * DD + lane * 2);
    uint32_t ni = negkey[i] & (NN - 1);
    float2 gv = *(const float2*)(inp + (size_t)ni * DD + lane * 2);
    float e0 = c.x - x.x + 1e-6f, e1 = c.y - x.y + 1e-6f;
    float f0 = c.x - gv.x + 1e-6f, f1 = c.y - gv.y + 1e-6f;
    float dap = e0 * e0 + e1 * e1;
    float dan = f0 * f0 + f1 * f1;
#pragma unroll
    for (int d = 32; d; d >>= 1) {
      dap += __shfl_down(dap, d);
      dan += __shfl_down(dan, d);
    }
    if (lane == 0) local += fmaxf(sqrtf(dap) - sqrtf(dan) + 0.3f, 0.f);
  }
  if (lane == 0) lds[w] = local;
  __syncthreads();
  if (tid == 0) atomicAdd(out, (lds[0] + lds[1] + lds[2] + lds[3]) * (1.0f / 8192.0f));
}

extern "C" void kernel_launch(void* const* d_in, const int* in_sizes, int n_in,
                              void* d_out, int out_size, void* d_ws, size_t ws_size,
                              hipStream_t stream) {
  (void)in_sizes; (void)n_in; (void)out_size; (void)ws_size;
  const float* inp = (const float*)d_in[0];
  const int* sim = (const int*)d_in[1];
  float* out = (float*)d_out;
  char* ws = (char*)d_ws;

  uint32_t* bmT     = (uint32_t*)ws;                                   // 8 MB  [kword][row]
  float* part       = (float*)(ws + (8u << 20));                       // 32 MB (8 K-splits)
  float* centers    = (float*)(ws + (40u << 20));                      // 4 MB
  uint16_t* inp_bf  = (uint16_t*)(ws + (44u << 20));                   // 2 MB
  uint16_t* inpT_bf = (uint16_t*)(ws + (46u << 20));                   // 2 MB
  uint16_t* cen_bf  = (uint16_t*)(ws + (48u << 20));                   // 2 MB
  float* x2p        = (float*)(ws + (50u << 20));                      // 32 KB
  uint32_t* counts4 = (uint32_t*)(ws + (50u << 20) + 32768u);          // 128 KB (4 slices)
  uint32_t* negkey  = (uint32_t*)(ws + (50u << 20) + 196608u);         // 32 KB

  k_prep_bitgen<<<640, 256, 0, stream>>>(inp, sim, inp_bf, inpT_bf, x2p, bmT, counts4, negkey, out);
  k_gemm1<<<dim3(64, 8), 256, 0, stream>>>(inpT_bf, bmT, part);
  k_reduce<<<1024, 256, 0, stream>>>(part, counts4, centers, cen_bf);
  k_argmin<<<dim3(64, 8), 256, 0, stream>>>(cen_bf, inp_bf, bmT, x2p, negkey);
  k_loss<<<512, 256, 0, stream>>>(centers, inp, negkey, out);
}